// Round 13
// baseline (223.874 us; speedup 1.0000x reference)
//
#include <hip/hip_runtime.h>
#include <hip/hip_bf16.h>

typedef __attribute__((ext_vector_type(8))) short short8;
typedef __attribute__((ext_vector_type(4))) float f32x4;
typedef __attribute__((ext_vector_type(4))) unsigned short u16x4;

__device__ __forceinline__ unsigned short f2bf(float f) {
  union { float f; unsigned u; } v; v.f = f;
  unsigned r = v.u + 0x7fffu + ((v.u >> 16) & 1u);
  return (unsigned short)(r >> 16);
}

// C = A * Bt^T. WM*WN waves, wave-tile (MI*16) x 64, BK=64, NBUF=2 dbuf,
// counted vmcnt (prefetch in flight across barriers), setprio on MFMA.
// bn-MAJOR linear block mapping (L2 panel reuse per XCD).
// Pass A: EPI=0, WM=4,WN=2,MI=2 -> 128x128, 512 thr, 64 KB LDS, 2 blk/CU.
//   Epilogue: w = exp2(-dist*rt2), W bf16 via swizzled LDS bounce -> cached
//   stores (pass B re-reads W); row-sum partials (unique writer).
// Pass B: EPI=1, WM=1,WN=8,MI=4 -> 64x512 (FULL D in one block -> W read
//   exactly ONCE from HBM), 512 thr, 144 KB LDS, 1 blk/CU.
//   Epilogue: out fp32 * 1/(denin+1e-8) via LDS bounce -> NT stores.
// LDS staging swizzle: row r (8x16B chunks) holds global chunk c^(r&7) at
// slot c; applied global-side (linear gload_lds dest) + reader-side.
template <int EPI, int WM, int WN, int MI, int BK, int NBUF, int MINW>
__global__ __launch_bounds__(WM * WN * 64, MINW) void rbf_gemm(
    const unsigned short* __restrict__ A, const unsigned short* __restrict__ Bt,
    int Ncols, int K,
    const float* __restrict__ xsq, const float* __restrict__ psq,
    const float* __restrict__ rtemp, unsigned short* __restrict__ Wout,
    float* __restrict__ part, int Mtot, const float* __restrict__ denin,
    float* __restrict__ outp, int row0, int ldOut) {
  constexpr int NT = WM * WN * 64;       // threads per block
  constexpr int BM = WM * MI * 16;
  constexpr int BN = WN * 64;
  constexpr int CH = BK / 8;             // 16B chunks per row
  constexpr int CMASK = CH - 1;
  constexpr int AIT = BM * CH / NT;      // A staging iters
  constexpr int BIT = BN * CH / NT;      // B staging iters
  constexpr int LOADS = AIT + BIT;
  constexpr int KS = BK / 32;            // k-frags per step
  constexpr int ASZ = BM * BK;
  constexpr int TSZ = (BM + BN) * BK;    // elems per buffer
  constexpr int BOUNCE = EPI == 1 ? BM * BN * 2 : BM * BN;  // shorts
  constexpr int SELEMS = NBUF * TSZ > BOUNCE ? NBUF * TSZ : BOUNCE;
  __shared__ __align__(16) unsigned short smem[SELEMS];

  const int t = threadIdx.x;
  const int lane = t & 63, wid = t >> 6;
  const int wm = wid / WN, wn = wid % WN;
  const int lr = lane & 15, lg = lane >> 4;

  // bn-major mapping: consecutive blocks share bn and walk bm.
  const int nbm = gridDim.x / (Ncols / BN);
  const int bm = blockIdx.x % nbm;
  const int bn = blockIdx.x / nbm;

  const unsigned short* Ab = A + (size_t)bm * BM * K;
  const unsigned short* Bb = Bt + (size_t)bn * BN * K;

  // staging source pointers (swizzled chunk); bumped by +BK per stage
  const unsigned short* gA[AIT];
  const unsigned short* gB[BIT];
#pragma unroll
  for (int i = 0; i < AIT; ++i) {
    const int idx = i * NT + t;
    const int r = idx / CH, c = idx & CMASK;
    gA[i] = Ab + (size_t)r * K + ((c ^ (r & CMASK)) << 3);
  }
#pragma unroll
  for (int i = 0; i < BIT; ++i) {
    const int idx = i * NT + t;
    const int r = idx / CH, c = idx & CMASK;
    gB[i] = Bb + (size_t)r * K + ((c ^ (r & CMASK)) << 3);
  }
  const int dwave = wid << 9;  // wave-uniform LDS elem base (64 lanes * 16B)

  // fragment LDS element offsets (reader applies same swizzle)
  int offA[MI][KS], offB[4][KS];
#pragma unroll
  for (int mi = 0; mi < MI; ++mi) {
    const int ar = wm * (MI * 16) + mi * 16 + lr;
#pragma unroll
    for (int ks = 0; ks < KS; ++ks)
      offA[mi][ks] = ar * BK + ((((ks << 2) | lg) ^ (ar & CMASK)) << 3);
  }
#pragma unroll
  for (int ni = 0; ni < 4; ++ni) {
    const int br = wn * 64 + ni * 16 + lr;
#pragma unroll
    for (int ks = 0; ks < KS; ++ks)
      offB[ni][ks] = ASZ + br * BK + ((((ks << 2) | lg) ^ (br & CMASK)) << 3);
  }

  f32x4 acc[MI][4];
#pragma unroll
  for (int i = 0; i < MI; ++i)
#pragma unroll
    for (int j = 0; j < 4; ++j) acc[i][j] = (f32x4){0.f, 0.f, 0.f, 0.f};

  // STAGE issues from current gA/gB then bumps them by BK.
#define STAGE(bo)                                                                      \
  do {                                                                                 \
    _Pragma("unroll")                                                                  \
    for (int i = 0; i < AIT; ++i) {                                                    \
      __builtin_amdgcn_global_load_lds(                                                \
          (const __attribute__((address_space(1))) void*)gA[i],                        \
          (__attribute__((address_space(3))) void*)(smem + (bo) + i * (NT * 8) + dwave), \
          16, 0, 0);                                                                   \
      gA[i] += BK;                                                                     \
    }                                                                                  \
    _Pragma("unroll")                                                                  \
    for (int i = 0; i < BIT; ++i) {                                                    \
      __builtin_amdgcn_global_load_lds(                                                \
          (const __attribute__((address_space(1))) void*)gB[i],                        \
          (__attribute__((address_space(3))) void*)(smem + (bo) + ASZ + i * (NT * 8) + dwave), \
          16, 0, 0);                                                                   \
      gB[i] += BK;                                                                     \
    }                                                                                  \
  } while (0)

  const int nsteps = K / BK;
  STAGE(0);  // prologue
  unsigned buf = 0;
  for (int s = 0; s < nsteps; ++s) {
    if (s + 1 < nsteps) {
      STAGE(buf ^ TSZ);  // prefetch next K-tile; stays in flight over MFMA
      asm volatile("s_waitcnt vmcnt(%0)" :: "i"(LOADS) : "memory");
    } else {
      asm volatile("s_waitcnt vmcnt(0)" ::: "memory");
    }
    __builtin_amdgcn_s_barrier();       // all waves' stage(s) landed
    const unsigned short* sb = smem + buf;
    __builtin_amdgcn_s_setprio(1);
#pragma unroll
    for (int ks = 0; ks < KS; ++ks) {
      short8 af[MI], bf[4];
#pragma unroll
      for (int mi = 0; mi < MI; ++mi) af[mi] = *(const short8*)&sb[offA[mi][ks]];
#pragma unroll
      for (int ni = 0; ni < 4; ++ni) bf[ni] = *(const short8*)&sb[offB[ni][ks]];
#pragma unroll
      for (int mi = 0; mi < MI; ++mi)
#pragma unroll
        for (int ni = 0; ni < 4; ++ni)
          acc[mi][ni] = __builtin_amdgcn_mfma_f32_16x16x32_bf16(af[mi], bf[ni],
                                                                acc[mi][ni], 0, 0, 0);
    }
    __builtin_amdgcn_s_setprio(0);
    asm volatile("s_waitcnt lgkmcnt(0)" ::: "memory");  // ds_reads drained
    __builtin_amdgcn_s_barrier();       // safe to overwrite buf next iter
    buf ^= TSZ;
  }
#undef STAGE

  if (EPI == 0) {
    // cross -> dist -> weight -> swizzled LDS bounce; per-row partial sums.
    float ps[4], rt[4];
#pragma unroll
    for (int ni = 0; ni < 4; ++ni) {
      const int col = bn * BN + wn * 64 + ni * 16 + lr;
      ps[ni] = psq[col];
      rt[ni] = rtemp[col];  // log2e / effective_temp
    }
    float* slice = part + (size_t)(bn * WN + wn) * Mtot;
#pragma unroll
    for (int mi = 0; mi < MI; ++mi) {
#pragma unroll
      for (int j = 0; j < 4; ++j) {
        const int lrow = wm * (MI * 16) + mi * 16 + lg * 4 + j;
        const int grow = row0 + bm * BM + lrow;
        const float xq = xsq[grow];
        float rsv = 0.f;
#pragma unroll
        for (int ni = 0; ni < 4; ++ni) {
          const int lcol = wn * 64 + ni * 16 + lr;
          float d2 = xq + ps[ni] - 2.0f * acc[mi][ni][j];
          float dist = __builtin_amdgcn_sqrtf(fmaxf(d2, 0.0f));
          float w = __builtin_amdgcn_exp2f(-dist * rt[ni]);
          smem[lrow * BN + (((lcol >> 3) ^ (lrow & 7)) << 3) + (lcol & 7)] = f2bf(w);
          rsv += w;
        }
        rsv += __shfl_xor(rsv, 1);
        rsv += __shfl_xor(rsv, 2);
        rsv += __shfl_xor(rsv, 4);
        rsv += __shfl_xor(rsv, 8);
        if (lr == 0) slice[grow] = rsv;
      }
    }
    __syncthreads();
    // coalesced cached copy-out (W re-read by pass B)
    constexpr int HB = BN / 8;
#pragma unroll
    for (int i = 0; i < BM * BN / 8 / NT; ++i) {
      const int id = i * NT + t;
      const int r = id / HB, h = id % HB;
      short8 v = *(const short8*)&smem[r * BN + ((h ^ (r & 7)) << 3)];
      *(short8*)&Wout[(size_t)(bm * BM + r) * ldOut + bn * BN + h * 8] = v;
    }
  } else {
    // scale by 1/denom at copy-out; bounce fp32 tile for full-line NT stores
    float* smemf = (float*)smem;
#pragma unroll
    for (int mi = 0; mi < MI; ++mi)
#pragma unroll
      for (int j = 0; j < 4; ++j) {
        const int lrow = wm * (MI * 16) + mi * 16 + lg * 4 + j;
#pragma unroll
        for (int ni = 0; ni < 4; ++ni) {
          const int lcol = wn * 64 + ni * 16 + lr;
          smemf[lrow * BN + (((lcol >> 2) ^ (lrow & 7)) << 2) + (lcol & 3)] =
              acc[mi][ni][j];
        }
      }
    __syncthreads();
    constexpr int HB4 = BN / 4;
#pragma unroll
    for (int i = 0; i < BM * BN / 4 / NT; ++i) {
      const int id = i * NT + t;
      const int r = id / HB4, h = id % HB4;
      const int grow = row0 + bm * BM + r;
      const float rd = 1.0f / (denin[grow] + 1e-8f);
      f32x4 v = *(const f32x4*)&smemf[r * BN + ((h ^ (r & 7)) << 2)];
      v *= rd;
      __builtin_nontemporal_store(v,
          (f32x4*)&outp[(size_t)grow * ldOut + bn * BN + h * 4]);
    }
  }
}

// denom[m] = sum_s part[s][m]
__global__ void reduce_denom(const float* __restrict__ part, float* __restrict__ denom,
                             int Mtot, int row0, int S) {
  const int m = row0 + blockIdx.x * 128 + threadIdx.x;
  float s = 0.f;
  for (int i = 0; i < S; ++i) s += part[(size_t)i * Mtot + m];
  denom[m] = s;
}

// One block per row: cast fp32 row -> bf16, compute sum of squares.
__global__ void prep_rows(const float* __restrict__ in, unsigned short* __restrict__ outb,
                          float* __restrict__ sq, int D) {
  const int row = blockIdx.x;
  const int t = threadIdx.x;
  const float4 v = ((const float4*)(in + (size_t)row * D))[t];
  u16x4 o = {f2bf(v.x), f2bf(v.y), f2bf(v.z), f2bf(v.w)};
  *(u16x4*)(outb + (size_t)row * D + t * 4) = o;
  float s = v.x * v.x + v.y * v.y + v.z * v.z + v.w * v.w;
  for (int off = 32; off; off >>= 1) s += __shfl_xor(s, off);
  __shared__ float ws[16];
  if ((t & 63) == 0) ws[t >> 6] = s;
  __syncthreads();
  if (t == 0) {
    float tot = 0.f;
    const int nw = blockDim.x >> 6;
    for (int i = 0; i < nw; ++i) tot += ws[i];
    sq[row] = tot;
  }
}

// rtemp = log2(e) / ((|T|+0.1)*scale): folds the exp->exp2 conversion.
__global__ void prep_scale(const float* __restrict__ tmp, const float* __restrict__ sc,
                           float* __restrict__ rtemp, int N) {
  const int i = blockIdx.x * blockDim.x + threadIdx.x;
  if (i < N) rtemp[i] = 1.4426950408889634f / ((fabsf(tmp[i]) + 0.1f) * sc[i]);
}

// Transpose values [N][D] fp32 -> vT [D][N] bf16
__global__ void prep_vT(const float* __restrict__ vals, unsigned short* __restrict__ vT,
                        int N, int D) {
  __shared__ float tile[32][33];
  const int nt = blockIdx.x, dt = blockIdx.y;
  const int tx = threadIdx.x, ty = threadIdx.y;  // (32, 8)
#pragma unroll
  for (int i = 0; i < 4; ++i) {
    int r = nt * 32 + ty + i * 8;
    tile[ty + i * 8][tx] = vals[(size_t)r * D + dt * 32 + tx];
  }
  __syncthreads();
#pragma unroll
  for (int i = 0; i < 4; ++i) {
    int d = dt * 32 + ty + i * 8;
    vT[(size_t)d * N + nt * 32 + tx] = f2bf(tile[tx][ty + i * 8]);
  }
}

extern "C" void kernel_launch(void* const* d_in, const int* in_sizes, int n_in,
                              void* d_out, int out_size, void* d_ws, size_t ws_size,
                              hipStream_t stream) {
  const float* x = (const float*)d_in[0];
  const float* pos = (const float*)d_in[1];
  const float* vals = (const float*)d_in[2];
  const float* temp = (const float*)d_in[3];
  const float* nsc = (const float*)d_in[4];
  float* out = (float*)d_out;

  const int N = in_sizes[3];          // 4096
  const int D = in_sizes[1] / N;      // 512
  const int M = in_sizes[0] / D;      // 16384
  const int S = 2 * (N / 128);        // partial slices (64): BN=128, WN=2

  char* ws = (char*)d_ws;
  size_t off = 0;
  auto alloc = [&](size_t bytes) {
    void* p = ws + off;
    off = (off + bytes + 255) & ~(size_t)255;
    return p;
  };
  unsigned short* xb = (unsigned short*)alloc((size_t)M * D * 2);
  unsigned short* pb = (unsigned short*)alloc((size_t)N * D * 2);
  unsigned short* vT = (unsigned short*)alloc((size_t)D * N * 2);
  float* xsq = (float*)alloc((size_t)M * 4);
  float* psq = (float*)alloc((size_t)N * 4);
  float* rtemp = (float*)alloc((size_t)N * 4);
  float* denom = (float*)alloc((size_t)M * 4);
  float* part = (float*)alloc((size_t)S * M * 4);

  size_t avail = ws_size > off ? ws_size - off : 0;
  long long mc_ll = (long long)(avail / ((size_t)N * 2));
  int Mc = (int)((mc_ll / 128) * 128);
  if (Mc > M) Mc = M;
  if (Mc < 128) Mc = 128;  // minimal fallback
  unsigned short* W = (unsigned short*)alloc((size_t)Mc * N * 2);

  prep_rows<<<M, D / 4, 0, stream>>>(x, xb, xsq, D);
  prep_rows<<<N, D / 4, 0, stream>>>(pos, pb, psq, D);
  prep_scale<<<(N + 255) / 256, 256, 0, stream>>>(temp, nsc, rtemp, N);
  dim3 tg(N / 32, D / 32);
  prep_vT<<<tg, dim3(32, 8), 0, stream>>>(vals, vT, N, D);

  for (int row0 = 0; row0 < M; row0 += Mc) {
    const int mc = (M - row0) < Mc ? (M - row0) : Mc;
    // pass A: 128x128, 8 waves (4x2), bn-major (proven 122 us config)
    const int g1 = (mc / 128) * (N / 128);
    rbf_gemm<0, 4, 2, 2, 64, 2, 4><<<g1, 512, 0, stream>>>(
        xb + (size_t)row0 * D, pb, N, D, xsq, psq, rtemp, W, part, M,
        nullptr, nullptr, row0, N);
    reduce_denom<<<mc / 128, 128, 0, stream>>>(part, denom, M, row0, S);
    // pass B: 64x512 (full D per block -> W read once), 1 blk/CU
    const int g2 = (mc / 64) * (D / 512);
    rbf_gemm<1, 1, 8, 4, 64, 2, 2><<<g2, 512, 0, stream>>>(
        W, vT, D, N, nullptr, nullptr, nullptr, nullptr,
        part, M, denom, out, row0, D);
  }
}

// Round 14
// 220.853 us; speedup vs baseline: 1.0137x; 1.0137x over previous
//
#include <hip/hip_runtime.h>
#include <hip/hip_bf16.h>

typedef __attribute__((ext_vector_type(8))) short short8;
typedef __attribute__((ext_vector_type(4))) float f32x4;
typedef __attribute__((ext_vector_type(4))) unsigned short u16x4;

__device__ __forceinline__ unsigned short f2bf(float f) {
  union { float f; unsigned u; } v; v.f = f;
  unsigned r = v.u + 0x7fffu + ((v.u >> 16) & 1u);
  return (unsigned short)(r >> 16);
}

#define GLL(src, dst)                                                     \
  __builtin_amdgcn_global_load_lds(                                       \
      (const __attribute__((address_space(1))) void*)(src),               \
      (__attribute__((address_space(3))) void*)(dst), 16, 0, 0)
#define BAR __builtin_amdgcn_s_barrier()
#define LGKM0                                                             \
  do {                                                                    \
    asm volatile("s_waitcnt lgkmcnt(0)" ::: "memory");                    \
    __builtin_amdgcn_sched_barrier(0);                                    \
  } while (0)
#define VMC(n) asm volatile("s_waitcnt vmcnt(" #n ")" ::: "memory")

// ---------------- Pass A: 8-phase 256x256 fused dist/exp GEMM ----------------
// 8 waves (2M x 4N), wave-tile 128x64, BK=64, LDS 2 x 64KB dbuf.
// Per K-tile: 4 phases. Phase p: {ds_read A-frags mi{2p,2p+1} (+ all B in P1),
// stage one slice of NEXT tile into the OTHER buffer (order B, Aq01, Aq2, Aq3
// = next tile's consumption order), BAR, lgkmcnt(0)+sched_barrier, setprio(1),
// 16 MFMA, setprio(0), counted vmcnt, BAR}. Boundary vmcnt(2), mid vmcnt(7):
// staged loads remain >=4 phases in flight; never drain to 0 mid-loop.
// Staging swizzle: row r chunk slot c holds global chunk c^(r&7) (source-side
// swizzle, linear LDS dest); readers XOR the same way. bn-major block map.
__global__ __launch_bounds__(512, 2) void rbf_qk8p(
    const unsigned short* __restrict__ A, const unsigned short* __restrict__ Bt,
    int Ncols, int K,
    const float* __restrict__ xsq, const float* __restrict__ psq,
    const float* __restrict__ rtemp, unsigned short* __restrict__ Wout,
    float* __restrict__ part, int Mtot, int row0, int ldOut) {
  constexpr int BK = 64;
  constexpr int ASZ = 256 * 64;        // A elems per K-tile
  constexpr int TSZ = 512 * 64;        // elems per buffer (A+B) = 64 KB
  __shared__ __align__(16) unsigned short smem[2 * TSZ];  // 128 KB

  const int t = threadIdx.x;
  const int lane = t & 63, wid = t >> 6;
  const int wm = wid >> 2, wn = wid & 3;   // 2M x 4N waves
  const int lr = lane & 15, lg = lane >> 4;

  const int nbm = gridDim.x / (Ncols >> 8);
  const int bm = blockIdx.x % nbm;
  const int bn = blockIdx.x / nbm;

  const unsigned short* Ab = A + (size_t)bm * 256 * K;
  const unsigned short* Bb = Bt + (size_t)bn * 256 * K;

  // B staging: items h in {0,1} (rows h*128..+127), 2 loads each.
  const unsigned short* gB[4];
#pragma unroll
  for (int h = 0; h < 2; ++h)
#pragma unroll
    for (int i = 0; i < 2; ++i) {
      const int idx = i * 512 + t;
      const int r = h * 128 + (idx >> 3), c = idx & 7;
      gB[h * 2 + i] = Bb + (size_t)r * K + ((c ^ (r & 7)) << 3);
    }
  // A staging: items q (rows q*32..+31 and 128+q*32..+31), 1 load each.
  const unsigned short* gAq[4];
  {
    const int half = t >> 8, rl = (t & 255) >> 3, c = t & 7;
#pragma unroll
    for (int q = 0; q < 4; ++q) {
      const int R = half * 128 + q * 32 + rl;
      gAq[q] = Ab + (size_t)R * K + ((c ^ (R & 7)) << 3);
    }
  }
  const int dwB = wid << 9;                                  // B dest base
  const int abase = ((wid >> 2) << 13) + ((wid & 3) << 9);   // A dest base

#define STB(bo)                                         \
  do {                                                  \
    GLL(gB[0], smem + (bo) + ASZ + dwB);                \
    gB[0] += BK;                                        \
    GLL(gB[1], smem + (bo) + ASZ + 4096 + dwB);         \
    gB[1] += BK;                                        \
    GLL(gB[2], smem + (bo) + ASZ + 8192 + dwB);         \
    gB[2] += BK;                                        \
    GLL(gB[3], smem + (bo) + ASZ + 12288 + dwB);        \
    gB[3] += BK;                                        \
  } while (0)
#define STA(bo, q)                                      \
  do {                                                  \
    GLL(gAq[q], smem + (bo) + abase + (q) * 2048);      \
    gAq[q] += BK;                                       \
  } while (0)

  // fragment LDS element offsets (reader applies source-side swizzle)
  int offA[8][2], offB[4][2];
#pragma unroll
  for (int mi = 0; mi < 8; ++mi) {
    const int ar = wm * 128 + mi * 16 + lr;
#pragma unroll
    for (int ks = 0; ks < 2; ++ks)
      offA[mi][ks] = ar * 64 + ((((ks << 2) | lg) ^ (ar & 7)) << 3);
  }
#pragma unroll
  for (int ni = 0; ni < 4; ++ni) {
    const int br = wn * 64 + ni * 16 + lr;
#pragma unroll
    for (int ks = 0; ks < 2; ++ks)
      offB[ni][ks] = ASZ + br * 64 + ((((ks << 2) | lg) ^ (br & 7)) << 3);
  }

  f32x4 acc[8][4];
#pragma unroll
  for (int i = 0; i < 8; ++i)
#pragma unroll
    for (int j = 0; j < 4; ++j) acc[i][j] = (f32x4){0.f, 0.f, 0.f, 0.f};

#define PH_READS_A(p)                                   \
  afr[0][0] = *(const short8*)&sb[offA[2 * (p)][0]];    \
  afr[0][1] = *(const short8*)&sb[offA[2 * (p)][1]];    \
  afr[1][0] = *(const short8*)&sb[offA[2 * (p) + 1][0]]; \
  afr[1][1] = *(const short8*)&sb[offA[2 * (p) + 1][1]];
#define PH_MFMA(p)                                                            \
  __builtin_amdgcn_s_setprio(1);                                              \
  _Pragma("unroll") for (int ks = 0; ks < 2; ++ks)                            \
  _Pragma("unroll") for (int r = 0; r < 2; ++r)                               \
  _Pragma("unroll") for (int ni = 0; ni < 4; ++ni)                            \
      acc[2 * (p) + r][ni] = __builtin_amdgcn_mfma_f32_16x16x32_bf16(         \
          afr[r][ks], bfr[ni][ks], acc[2 * (p) + r][ni], 0, 0, 0);            \
  __builtin_amdgcn_s_setprio(0);

  const int nsteps = K / BK;
  const int last = nsteps - 1;
  // prologue: full tile 0 in consumption order; allow Aq2,Aq3 in flight.
  STB(0);
  STA(0, 0);
  STA(0, 1);
  STA(0, 2);
  STA(0, 3);
  VMC(2);
  BAR;

  for (int tt = 0; tt < nsteps; ++tt) {
    const int bo = (tt & 1) * TSZ, nbo = bo ^ TSZ;
    const bool st = tt + 1 < nsteps;
    const unsigned short* sb = smem + bo;
    short8 bfr[4][2], afr[2][2];
    // P1: all B + A mi0,1 ; stage B(next)
#pragma unroll
    for (int ni = 0; ni < 4; ++ni) {
      bfr[ni][0] = *(const short8*)&sb[offB[ni][0]];
      bfr[ni][1] = *(const short8*)&sb[offB[ni][1]];
    }
    PH_READS_A(0)
    if (st) STB(nbo);
    BAR;
    LGKM0;
    PH_MFMA(0)
    BAR;
    // P2: A mi2,3 ; stage Aq0,Aq1(next) ; ensure Aq2(cur) landed
    PH_READS_A(1)
    if (st) {
      STA(nbo, 0);
      STA(nbo, 1);
    }
    BAR;
    LGKM0;
    PH_MFMA(1)
    if (tt == last) {
      VMC(1);
    } else {
      VMC(7);
    }
    BAR;
    // P3: A mi4,5 ; stage Aq2(next) ; ensure Aq3(cur) landed
    PH_READS_A(2)
    if (st) STA(nbo, 2);
    BAR;
    LGKM0;
    PH_MFMA(2)
    if (tt == last) {
      VMC(0);
    } else {
      VMC(7);
    }
    BAR;
    // P4: A mi6,7 ; stage Aq3(next) ; boundary: allow Aq2,Aq3(next) in flight
    PH_READS_A(3)
    if (st) STA(nbo, 3);
    BAR;
    LGKM0;
    PH_MFMA(3)
    if (tt != last) {
      VMC(2);
    }
    BAR;
  }
#undef PH_READS_A
#undef PH_MFMA
#undef STB
#undef STA

  // epilogue: dist -> exp2 weight -> swizzled LDS bounce; row-sum partials.
  float ps[4], rt[4];
#pragma unroll
  for (int ni = 0; ni < 4; ++ni) {
    const int col = bn * 256 + wn * 64 + ni * 16 + lr;
    ps[ni] = psq[col];
    rt[ni] = rtemp[col];
  }
  float* slice = part + (size_t)(bn * 4 + wn) * Mtot;
#pragma unroll
  for (int mi = 0; mi < 8; ++mi) {
#pragma unroll
    for (int j = 0; j < 4; ++j) {
      const int lrow = wm * 128 + mi * 16 + lg * 4 + j;
      const int grow = row0 + bm * 256 + lrow;
      const float xq = xsq[grow];
      float rsv = 0.f;
#pragma unroll
      for (int ni = 0; ni < 4; ++ni) {
        const int lcol = wn * 64 + ni * 16 + lr;
        float d2 = xq + ps[ni] - 2.0f * acc[mi][ni][j];
        float dist = __builtin_amdgcn_sqrtf(fmaxf(d2, 0.0f));
        float w = __builtin_amdgcn_exp2f(-dist * rt[ni]);
        smem[lrow * 256 + (((lcol >> 3) ^ (lrow & 7)) << 3) + (lcol & 7)] = f2bf(w);
        rsv += w;
      }
      rsv += __shfl_xor(rsv, 1);
      rsv += __shfl_xor(rsv, 2);
      rsv += __shfl_xor(rsv, 4);
      rsv += __shfl_xor(rsv, 8);
      if (lr == 0) slice[grow] = rsv;
    }
  }
  __syncthreads();
#pragma unroll
  for (int i = 0; i < 16; ++i) {
    const int id = i * 512 + t;
    const int r = id >> 5, h = id & 31;
    short8 v = *(const short8*)&smem[r * 256 + ((h ^ (r & 7)) << 3)];
    *(short8*)&Wout[(size_t)(bm * 256 + r) * ldOut + bn * 256 + h * 8] = v;
  }
}

// ---------------- Pass B (round-12 proven template, EPI=1 only) ----------------
template <int EPI, int WM, int WN, int MI, int BK, int NBUF>
__global__ __launch_bounds__(WM * WN * 64, 4) void rbf_gemm(
    const unsigned short* __restrict__ A, const unsigned short* __restrict__ Bt,
    int Ncols, int K, const float* __restrict__ denin,
    float* __restrict__ outp, int row0, int ldOut) {
  constexpr int NT = WM * WN * 64;
  constexpr int BM = WM * MI * 16;
  constexpr int BN = WN * 64;
  constexpr int CH = BK / 8;
  constexpr int CMASK = CH - 1;
  constexpr int AIT = BM * CH / NT;
  constexpr int BIT = BN * CH / NT;
  constexpr int LOADS = AIT + BIT;
  constexpr int KS = BK / 32;
  constexpr int ASZ = BM * BK;
  constexpr int TSZ = (BM + BN) * BK;
  constexpr int BOUNCE = BM * BN * 2;
  constexpr int SELEMS = NBUF * TSZ > BOUNCE ? NBUF * TSZ : BOUNCE;
  __shared__ __align__(16) unsigned short smem[SELEMS];

  const int t = threadIdx.x;
  const int lane = t & 63, wid = t >> 6;
  const int wm = wid / WN, wn = wid % WN;
  const int lr = lane & 15, lg = lane >> 4;

  const int nbm = gridDim.x / (Ncols / BN);
  const int bm = blockIdx.x % nbm;
  const int bn = blockIdx.x / nbm;

  const unsigned short* Ab = A + (size_t)bm * BM * K;
  const unsigned short* Bb = Bt + (size_t)bn * BN * K;

  const unsigned short* gA[AIT];
  const unsigned short* gB[BIT];
#pragma unroll
  for (int i = 0; i < AIT; ++i) {
    const int idx = i * NT + t;
    const int r = idx / CH, c = idx & CMASK;
    gA[i] = Ab + (size_t)r * K + ((c ^ (r & CMASK)) << 3);
  }
#pragma unroll
  for (int i = 0; i < BIT; ++i) {
    const int idx = i * NT + t;
    const int r = idx / CH, c = idx & CMASK;
    gB[i] = Bb + (size_t)r * K + ((c ^ (r & CMASK)) << 3);
  }
  const int dwave = wid << 9;

  int offA[MI][KS], offB[4][KS];
#pragma unroll
  for (int mi = 0; mi < MI; ++mi) {
    const int ar = wm * (MI * 16) + mi * 16 + lr;
#pragma unroll
    for (int ks = 0; ks < KS; ++ks)
      offA[mi][ks] = ar * BK + ((((ks << 2) | lg) ^ (ar & CMASK)) << 3);
  }
#pragma unroll
  for (int ni = 0; ni < 4; ++ni) {
    const int br = wn * 64 + ni * 16 + lr;
#pragma unroll
    for (int ks = 0; ks < KS; ++ks)
      offB[ni][ks] = ASZ + br * BK + ((((ks << 2) | lg) ^ (br & CMASK)) << 3);
  }

  f32x4 acc[MI][4];
#pragma unroll
  for (int i = 0; i < MI; ++i)
#pragma unroll
    for (int j = 0; j < 4; ++j) acc[i][j] = (f32x4){0.f, 0.f, 0.f, 0.f};

#define STAGE(bo)                                                              \
  do {                                                                         \
    _Pragma("unroll") for (int i = 0; i < AIT; ++i) {                          \
      GLL(gA[i], smem + (bo) + i * (NT * 8) + dwave);                          \
      gA[i] += BK;                                                             \
    }                                                                          \
    _Pragma("unroll") for (int i = 0; i < BIT; ++i) {                          \
      GLL(gB[i], smem + (bo) + ASZ + i * (NT * 8) + dwave);                    \
      gB[i] += BK;                                                             \
    }                                                                          \
  } while (0)

  const int nsteps = K / BK;
  STAGE(0);
  unsigned buf = 0;
  for (int s = 0; s < nsteps; ++s) {
    if (s + 1 < nsteps) {
      STAGE(buf ^ TSZ);
      asm volatile("s_waitcnt vmcnt(%0)" :: "i"(LOADS) : "memory");
    } else {
      asm volatile("s_waitcnt vmcnt(0)" ::: "memory");
    }
    BAR;
    const unsigned short* sb = smem + buf;
    __builtin_amdgcn_s_setprio(1);
#pragma unroll
    for (int ks = 0; ks < KS; ++ks) {
      short8 af[MI], bf[4];
#pragma unroll
      for (int mi = 0; mi < MI; ++mi) af[mi] = *(const short8*)&sb[offA[mi][ks]];
#pragma unroll
      for (int ni = 0; ni < 4; ++ni) bf[ni] = *(const short8*)&sb[offB[ni][ks]];
#pragma unroll
      for (int mi = 0; mi < MI; ++mi)
#pragma unroll
        for (int ni = 0; ni < 4; ++ni)
          acc[mi][ni] = __builtin_amdgcn_mfma_f32_16x16x32_bf16(af[mi], bf[ni],
                                                                acc[mi][ni], 0, 0, 0);
    }
    __builtin_amdgcn_s_setprio(0);
    asm volatile("s_waitcnt lgkmcnt(0)" ::: "memory");
    BAR;
    buf ^= TSZ;
  }
#undef STAGE

  // scale by 1/denom at copy-out; bounce fp32 tile for full-line NT stores
  float* smemf = (float*)smem;
#pragma unroll
  for (int mi = 0; mi < MI; ++mi)
#pragma unroll
    for (int j = 0; j < 4; ++j) {
      const int lrow = wm * (MI * 16) + mi * 16 + lg * 4 + j;
#pragma unroll
      for (int ni = 0; ni < 4; ++ni) {
        const int lcol = wn * 64 + ni * 16 + lr;
        smemf[lrow * BN + (((lcol >> 2) ^ (lrow & 7)) << 2) + (lcol & 3)] =
            acc[mi][ni][j];
      }
    }
  __syncthreads();
  constexpr int HB4 = BN / 4;
#pragma unroll
  for (int i = 0; i < BM * BN / 4 / NT; ++i) {
    const int id = i * NT + t;
    const int r = id / HB4, h = id % HB4;
    const int grow = row0 + bm * BM + r;
    const float rd = 1.0f / (denin[grow] + 1e-8f);
    f32x4 v = *(const f32x4*)&smemf[r * BN + ((h ^ (r & 7)) << 2)];
    v *= rd;
    __builtin_nontemporal_store(v,
        (f32x4*)&outp[(size_t)grow * ldOut + bn * BN + h * 4]);
  }
}

// denom[m] = sum_s part[s][m]
__global__ void reduce_denom(const float* __restrict__ part, float* __restrict__ denom,
                             int Mtot, int row0, int S) {
  const int m = row0 + blockIdx.x * 128 + threadIdx.x;
  float s = 0.f;
  for (int i = 0; i < S; ++i) s += part[(size_t)i * Mtot + m];
  denom[m] = s;
}

__global__ void prep_rows(const float* __restrict__ in, unsigned short* __restrict__ outb,
                          float* __restrict__ sq, int D) {
  const int row = blockIdx.x;
  const int t = threadIdx.x;
  const float4 v = ((const float4*)(in + (size_t)row * D))[t];
  u16x4 o = {f2bf(v.x), f2bf(v.y), f2bf(v.z), f2bf(v.w)};
  *(u16x4*)(outb + (size_t)row * D + t * 4) = o;
  float s = v.x * v.x + v.y * v.y + v.z * v.z + v.w * v.w;
  for (int off = 32; off; off >>= 1) s += __shfl_xor(s, off);
  __shared__ float ws[16];
  if ((t & 63) == 0) ws[t >> 6] = s;
  __syncthreads();
  if (t == 0) {
    float tot = 0.f;
    const int nw = blockDim.x >> 6;
    for (int i = 0; i < nw; ++i) tot += ws[i];
    sq[row] = tot;
  }
}

// rtemp = log2(e) / ((|T|+0.1)*scale)
__global__ void prep_scale(const float* __restrict__ tmp, const float* __restrict__ sc,
                           float* __restrict__ rtemp, int N) {
  const int i = blockIdx.x * blockDim.x + threadIdx.x;
  if (i < N) rtemp[i] = 1.4426950408889634f / ((fabsf(tmp[i]) + 0.1f) * sc[i]);
}

// Transpose values [N][D] fp32 -> vT [D][N] bf16
__global__ void prep_vT(const float* __restrict__ vals, unsigned short* __restrict__ vT,
                        int N, int D) {
  __shared__ float tile[32][33];
  const int nt = blockIdx.x, dt = blockIdx.y;
  const int tx = threadIdx.x, ty = threadIdx.y;
#pragma unroll
  for (int i = 0; i < 4; ++i) {
    int r = nt * 32 + ty + i * 8;
    tile[ty + i * 8][tx] = vals[(size_t)r * D + dt * 32 + tx];
  }
  __syncthreads();
#pragma unroll
  for (int i = 0; i < 4; ++i) {
    int d = dt * 32 + ty + i * 8;
    vT[(size_t)d * N + nt * 32 + tx] = f2bf(tile[tx][ty + i * 8]);
  }
}

extern "C" void kernel_launch(void* const* d_in, const int* in_sizes, int n_in,
                              void* d_out, int out_size, void* d_ws, size_t ws_size,
                              hipStream_t stream) {
  const float* x = (const float*)d_in[0];
  const float* pos = (const float*)d_in[1];
  const float* vals = (const float*)d_in[2];
  const float* temp = (const float*)d_in[3];
  const float* nsc = (const float*)d_in[4];
  float* out = (float*)d_out;

  const int N = in_sizes[3];          // 4096
  const int D = in_sizes[1] / N;      // 512
  const int M = in_sizes[0] / D;      // 16384
  const int S = 4 * (N / 256);        // partial slices (64)

  char* ws = (char*)d_ws;
  size_t off = 0;
  auto alloc = [&](size_t bytes) {
    void* p = ws + off;
    off = (off + bytes + 255) & ~(size_t)255;
    return p;
  };
  unsigned short* xb = (unsigned short*)alloc((size_t)M * D * 2);
  unsigned short* pb = (unsigned short*)alloc((size_t)N * D * 2);
  unsigned short* vT = (unsigned short*)alloc((size_t)D * N * 2);
  float* xsq = (float*)alloc((size_t)M * 4);
  float* psq = (float*)alloc((size_t)N * 4);
  float* rtemp = (float*)alloc((size_t)N * 4);
  float* denom = (float*)alloc((size_t)M * 4);
  float* part = (float*)alloc((size_t)S * M * 4);

  size_t avail = ws_size > off ? ws_size - off : 0;
  long long mc_ll = (long long)(avail / ((size_t)N * 2));
  int Mc = (int)((mc_ll / 256) * 256);
  if (Mc > M) Mc = M;
  if (Mc < 256) Mc = 256;  // minimal fallback
  unsigned short* W = (unsigned short*)alloc((size_t)Mc * N * 2);

  prep_rows<<<M, D / 4, 0, stream>>>(x, xb, xsq, D);
  prep_rows<<<N, D / 4, 0, stream>>>(pos, pb, psq, D);
  prep_scale<<<(N + 255) / 256, 256, 0, stream>>>(temp, nsc, rtemp, N);
  dim3 tg(N / 32, D / 32);
  prep_vT<<<tg, dim3(32, 8), 0, stream>>>(vals, vT, N, D);

  for (int row0 = 0; row0 < M; row0 += Mc) {
    const int mc = (M - row0) < Mc ? (M - row0) : Mc;
    // pass A: 256x256 8-phase
    const int g1 = (mc / 256) * (N / 256);
    rbf_qk8p<<<g1, 512, 0, stream>>>(xb + (size_t)row0 * D, pb, N, D,
                                     xsq, psq, rtemp, W, part, M, row0, N);
    reduce_denom<<<mc / 128, 128, 0, stream>>>(part, denom, M, row0, S);
    // pass B: 128x256 (round-12 proven config)
    const int g2 = (mc / 128) * (D / 256);
    rbf_gemm<1, 2, 4, 4, 64, 2><<<g2, 512, 0, stream>>>(
        W, vT, D, N, denom, out, row0, D);
  }
}

// Round 15
// 206.345 us; speedup vs baseline: 1.0849x; 1.0703x over previous
//
#include <hip/hip_runtime.h>
#include <hip/hip_bf16.h>

typedef __attribute__((ext_vector_type(8))) short short8;
typedef __attribute__((ext_vector_type(4))) float f32x4;
typedef __attribute__((ext_vector_type(4))) unsigned short u16x4;

__device__ __forceinline__ unsigned short f2bf(float f) {
  union { float f; unsigned u; } v; v.f = f;
  unsigned r = v.u + 0x7fffu + ((v.u >> 16) & 1u);
  return (unsigned short)(r >> 16);
}

// C = A * Bt^T. WM*WN waves, wave-tile (MI*16) x 64, NBUF=2 dbuf,
// counted vmcnt (prefetch in flight across barriers), setprio on MFMA.
// bn-MAJOR linear block mapping (L2 panel reuse per XCD, round-12 proven).
// Pass A: EPI=0, WM=2,WN=4,MI=4,BK=32 -> 128x256, 512 thr, 64 KB LDS,
//   2 blk/CU. 2x work/block vs 128x128: prologue/epilogue amortized, and
//   ds_read:MFMA per step = 8:16 (was 12:16).
//   Epilogue: w = exp2(-dist*rt2), W bf16 via swizzled LDS bounce -> cached
//   stores (pass B re-reads W); row-sum partials (unique writer).
// Pass B: EPI=1, WM=2,WN=4,MI=4,BK=64 -> 128x256 (round-12 proven).
//   Epilogue: out fp32 * 1/(denin+1e-8) via LDS bounce -> NT stores.
// LDS staging swizzle: row r (CH x 16B chunks) holds global chunk c^(r&CMASK)
// at slot c; applied global-side (linear gload_lds dest) + reader-side.
template <int EPI, int WM, int WN, int MI, int BK, int NBUF>
__global__ __launch_bounds__(WM * WN * 64, 4) void rbf_gemm(
    const unsigned short* __restrict__ A, const unsigned short* __restrict__ Bt,
    int Ncols, int K,
    const float* __restrict__ xsq, const float* __restrict__ psq,
    const float* __restrict__ rtemp, unsigned short* __restrict__ Wout,
    float* __restrict__ part, int Mtot, const float* __restrict__ denin,
    float* __restrict__ outp, int row0, int ldOut) {
  constexpr int NT = WM * WN * 64;       // threads per block
  constexpr int BM = WM * MI * 16;
  constexpr int BN = WN * 64;
  constexpr int CH = BK / 8;             // 16B chunks per row
  constexpr int CMASK = CH - 1;
  constexpr int AIT = BM * CH / NT;      // A staging iters
  constexpr int BIT = BN * CH / NT;      // B staging iters
  constexpr int LOADS = AIT + BIT;
  constexpr int KS = BK / 32;            // k-frags per step
  constexpr int ASZ = BM * BK;
  constexpr int TSZ = (BM + BN) * BK;    // elems per buffer
  constexpr int BOUNCE = EPI == 1 ? BM * BN * 2 : BM * BN;  // shorts
  constexpr int SELEMS = NBUF * TSZ > BOUNCE ? NBUF * TSZ : BOUNCE;
  __shared__ __align__(16) unsigned short smem[SELEMS];

  const int t = threadIdx.x;
  const int lane = t & 63, wid = t >> 6;
  const int wm = wid / WN, wn = wid % WN;
  const int lr = lane & 15, lg = lane >> 4;

  // bn-major mapping: consecutive blocks share bn and walk bm.
  const int nbm = gridDim.x / (Ncols / BN);
  const int bm = blockIdx.x % nbm;
  const int bn = blockIdx.x / nbm;

  const unsigned short* Ab = A + (size_t)bm * BM * K;
  const unsigned short* Bb = Bt + (size_t)bn * BN * K;

  // staging source pointers (swizzled chunk); bumped by +BK per stage
  const unsigned short* gA[AIT];
  const unsigned short* gB[BIT];
#pragma unroll
  for (int i = 0; i < AIT; ++i) {
    const int idx = i * NT + t;
    const int r = idx / CH, c = idx & CMASK;
    gA[i] = Ab + (size_t)r * K + ((c ^ (r & CMASK)) << 3);
  }
#pragma unroll
  for (int i = 0; i < BIT; ++i) {
    const int idx = i * NT + t;
    const int r = idx / CH, c = idx & CMASK;
    gB[i] = Bb + (size_t)r * K + ((c ^ (r & CMASK)) << 3);
  }
  const int dwave = wid << 9;  // wave-uniform LDS elem base (64 lanes * 16B)

  // fragment LDS element offsets (reader applies same swizzle)
  int offA[MI][KS], offB[4][KS];
#pragma unroll
  for (int mi = 0; mi < MI; ++mi) {
    const int ar = wm * (MI * 16) + mi * 16 + lr;
#pragma unroll
    for (int ks = 0; ks < KS; ++ks)
      offA[mi][ks] = ar * BK + ((((ks << 2) | lg) ^ (ar & CMASK)) << 3);
  }
#pragma unroll
  for (int ni = 0; ni < 4; ++ni) {
    const int br = wn * 64 + ni * 16 + lr;
#pragma unroll
    for (int ks = 0; ks < KS; ++ks)
      offB[ni][ks] = ASZ + br * BK + ((((ks << 2) | lg) ^ (br & CMASK)) << 3);
  }

  f32x4 acc[MI][4];
#pragma unroll
  for (int i = 0; i < MI; ++i)
#pragma unroll
    for (int j = 0; j < 4; ++j) acc[i][j] = (f32x4){0.f, 0.f, 0.f, 0.f};

  // STAGE issues from current gA/gB then bumps them by BK.
#define STAGE(bo)                                                                      \
  do {                                                                                 \
    _Pragma("unroll")                                                                  \
    for (int i = 0; i < AIT; ++i) {                                                    \
      __builtin_amdgcn_global_load_lds(                                                \
          (const __attribute__((address_space(1))) void*)gA[i],                        \
          (__attribute__((address_space(3))) void*)(smem + (bo) + i * (NT * 8) + dwave), \
          16, 0, 0);                                                                   \
      gA[i] += BK;                                                                     \
    }                                                                                  \
    _Pragma("unroll")                                                                  \
    for (int i = 0; i < BIT; ++i) {                                                    \
      __builtin_amdgcn_global_load_lds(                                                \
          (const __attribute__((address_space(1))) void*)gB[i],                        \
          (__attribute__((address_space(3))) void*)(smem + (bo) + ASZ + i * (NT * 8) + dwave), \
          16, 0, 0);                                                                   \
      gB[i] += BK;                                                                     \
    }                                                                                  \
  } while (0)

  const int nsteps = K / BK;
  STAGE(0);  // prologue
  unsigned buf = 0;
  for (int s = 0; s < nsteps; ++s) {
    if (s + 1 < nsteps) {
      STAGE(buf ^ TSZ);  // prefetch next K-tile; stays in flight over MFMA
      asm volatile("s_waitcnt vmcnt(%0)" :: "i"(LOADS) : "memory");
    } else {
      asm volatile("s_waitcnt vmcnt(0)" ::: "memory");
    }
    __builtin_amdgcn_s_barrier();       // all waves' stage(s) landed
    const unsigned short* sb = smem + buf;
    __builtin_amdgcn_s_setprio(1);
#pragma unroll
    for (int ks = 0; ks < KS; ++ks) {
      short8 af[MI], bf[4];
#pragma unroll
      for (int mi = 0; mi < MI; ++mi) af[mi] = *(const short8*)&sb[offA[mi][ks]];
#pragma unroll
      for (int ni = 0; ni < 4; ++ni) bf[ni] = *(const short8*)&sb[offB[ni][ks]];
#pragma unroll
      for (int mi = 0; mi < MI; ++mi)
#pragma unroll
        for (int ni = 0; ni < 4; ++ni)
          acc[mi][ni] = __builtin_amdgcn_mfma_f32_16x16x32_bf16(af[mi], bf[ni],
                                                                acc[mi][ni], 0, 0, 0);
    }
    __builtin_amdgcn_s_setprio(0);
    asm volatile("s_waitcnt lgkmcnt(0)" ::: "memory");  // ds_reads drained
    __builtin_amdgcn_s_barrier();       // safe to overwrite buf next iter
    buf ^= TSZ;
  }
#undef STAGE

  if (EPI == 0) {
    // cross -> dist -> weight -> swizzled LDS bounce; per-row partial sums.
    float ps[4], rt[4];
#pragma unroll
    for (int ni = 0; ni < 4; ++ni) {
      const int col = bn * BN + wn * 64 + ni * 16 + lr;
      ps[ni] = psq[col];
      rt[ni] = rtemp[col];  // log2e / effective_temp
    }
    float* slice = part + (size_t)(bn * WN + wn) * Mtot;
#pragma unroll
    for (int mi = 0; mi < MI; ++mi) {
#pragma unroll
      for (int j = 0; j < 4; ++j) {
        const int lrow = wm * (MI * 16) + mi * 16 + lg * 4 + j;
        const int grow = row0 + bm * BM + lrow;
        const float xq = xsq[grow];
        float rsv = 0.f;
#pragma unroll
        for (int ni = 0; ni < 4; ++ni) {
          const int lcol = wn * 64 + ni * 16 + lr;
          float d2 = xq + ps[ni] - 2.0f * acc[mi][ni][j];
          float dist = __builtin_amdgcn_sqrtf(fmaxf(d2, 0.0f));
          float w = __builtin_amdgcn_exp2f(-dist * rt[ni]);
          smem[lrow * BN + (((lcol >> 3) ^ (lrow & 7)) << 3) + (lcol & 7)] = f2bf(w);
          rsv += w;
        }
        rsv += __shfl_xor(rsv, 1);
        rsv += __shfl_xor(rsv, 2);
        rsv += __shfl_xor(rsv, 4);
        rsv += __shfl_xor(rsv, 8);
        if (lr == 0) slice[grow] = rsv;
      }
    }
    __syncthreads();
    // coalesced cached copy-out (W re-read by pass B)
    constexpr int HB = BN / 8;
#pragma unroll
    for (int i = 0; i < BM * BN / 8 / NT; ++i) {
      const int id = i * NT + t;
      const int r = id / HB, h = id % HB;
      short8 v = *(const short8*)&smem[r * BN + ((h ^ (r & 7)) << 3)];
      *(short8*)&Wout[(size_t)(bm * BM + r) * ldOut + bn * BN + h * 8] = v;
    }
  } else {
    // scale by 1/denom at copy-out; bounce fp32 tile for full-line NT stores
    float* smemf = (float*)smem;
#pragma unroll
    for (int mi = 0; mi < MI; ++mi)
#pragma unroll
      for (int j = 0; j < 4; ++j) {
        const int lrow = wm * (MI * 16) + mi * 16 + lg * 4 + j;
#pragma unroll
        for (int ni = 0; ni < 4; ++ni) {
          const int lcol = wn * 64 + ni * 16 + lr;
          smemf[lrow * BN + (((lcol >> 2) ^ (lrow & 7)) << 2) + (lcol & 3)] =
              acc[mi][ni][j];
        }
      }
    __syncthreads();
    constexpr int HB4 = BN / 4;
#pragma unroll
    for (int i = 0; i < BM * BN / 4 / NT; ++i) {
      const int id = i * NT + t;
      const int r = id / HB4, h = id % HB4;
      const int grow = row0 + bm * BM + r;
      const float rd = 1.0f / (denin[grow] + 1e-8f);
      f32x4 v = *(const f32x4*)&smemf[r * BN + ((h ^ (r & 7)) << 2)];
      v *= rd;
      __builtin_nontemporal_store(v,
          (f32x4*)&outp[(size_t)grow * ldOut + bn * BN + h * 4]);
    }
  }
}

// denom[m] = sum_s part[s][m]
__global__ void reduce_denom(const float* __restrict__ part, float* __restrict__ denom,
                             int Mtot, int row0, int S) {
  const int m = row0 + blockIdx.x * 128 + threadIdx.x;
  float s = 0.f;
  for (int i = 0; i < S; ++i) s += part[(size_t)i * Mtot + m];
  denom[m] = s;
}

// One block per row: cast fp32 row -> bf16, compute sum of squares.
__global__ void prep_rows(const float* __restrict__ in, unsigned short* __restrict__ outb,
                          float* __restrict__ sq, int D) {
  const int row = blockIdx.x;
  const int t = threadIdx.x;
  const float4 v = ((const float4*)(in + (size_t)row * D))[t];
  u16x4 o = {f2bf(v.x), f2bf(v.y), f2bf(v.z), f2bf(v.w)};
  *(u16x4*)(outb + (size_t)row * D + t * 4) = o;
  float s = v.x * v.x + v.y * v.y + v.z * v.z + v.w * v.w;
  for (int off = 32; off; off >>= 1) s += __shfl_xor(s, off);
  __shared__ float ws[16];
  if ((t & 63) == 0) ws[t >> 6] = s;
  __syncthreads();
  if (t == 0) {
    float tot = 0.f;
    const int nw = blockDim.x >> 6;
    for (int i = 0; i < nw; ++i) tot += ws[i];
    sq[row] = tot;
  }
}

// rtemp = log2(e) / ((|T|+0.1)*scale): folds the exp->exp2 conversion.
__global__ void prep_scale(const float* __restrict__ tmp, const float* __restrict__ sc,
                           float* __restrict__ rtemp, int N) {
  const int i = blockIdx.x * blockDim.x + threadIdx.x;
  if (i < N) rtemp[i] = 1.4426950408889634f / ((fabsf(tmp[i]) + 0.1f) * sc[i]);
}

// Transpose values [N][D] fp32 -> vT [D][N] bf16
__global__ void prep_vT(const float* __restrict__ vals, unsigned short* __restrict__ vT,
                        int N, int D) {
  __shared__ float tile[32][33];
  const int nt = blockIdx.x, dt = blockIdx.y;
  const int tx = threadIdx.x, ty = threadIdx.y;  // (32, 8)
#pragma unroll
  for (int i = 0; i < 4; ++i) {
    int r = nt * 32 + ty + i * 8;
    tile[ty + i * 8][tx] = vals[(size_t)r * D + dt * 32 + tx];
  }
  __syncthreads();
#pragma unroll
  for (int i = 0; i < 4; ++i) {
    int d = dt * 32 + ty + i * 8;
    vT[(size_t)d * N + nt * 32 + tx] = f2bf(tile[tx][ty + i * 8]);
  }
}

extern "C" void kernel_launch(void* const* d_in, const int* in_sizes, int n_in,
                              void* d_out, int out_size, void* d_ws, size_t ws_size,
                              hipStream_t stream) {
  const float* x = (const float*)d_in[0];
  const float* pos = (const float*)d_in[1];
  const float* vals = (const float*)d_in[2];
  const float* temp = (const float*)d_in[3];
  const float* nsc = (const float*)d_in[4];
  float* out = (float*)d_out;

  const int N = in_sizes[3];          // 4096
  const int D = in_sizes[1] / N;      // 512
  const int M = in_sizes[0] / D;      // 16384
  const int S = 4 * (N / 256);        // partial slices (64): BN=256, WN=4

  char* ws = (char*)d_ws;
  size_t off = 0;
  auto alloc = [&](size_t bytes) {
    void* p = ws + off;
    off = (off + bytes + 255) & ~(size_t)255;
    return p;
  };
  unsigned short* xb = (unsigned short*)alloc((size_t)M * D * 2);
  unsigned short* pb = (unsigned short*)alloc((size_t)N * D * 2);
  unsigned short* vT = (unsigned short*)alloc((size_t)D * N * 2);
  float* xsq = (float*)alloc((size_t)M * 4);
  float* psq = (float*)alloc((size_t)N * 4);
  float* rtemp = (float*)alloc((size_t)N * 4);
  float* denom = (float*)alloc((size_t)M * 4);
  float* part = (float*)alloc((size_t)S * M * 4);

  size_t avail = ws_size > off ? ws_size - off : 0;
  long long mc_ll = (long long)(avail / ((size_t)N * 2));
  int Mc = (int)((mc_ll / 128) * 128);
  if (Mc > M) Mc = M;
  if (Mc < 128) Mc = 128;  // minimal fallback
  unsigned short* W = (unsigned short*)alloc((size_t)Mc * N * 2);

  prep_rows<<<M, D / 4, 0, stream>>>(x, xb, xsq, D);
  prep_rows<<<N, D / 4, 0, stream>>>(pos, pb, psq, D);
  prep_scale<<<(N + 255) / 256, 256, 0, stream>>>(temp, nsc, rtemp, N);
  dim3 tg(N / 32, D / 32);
  prep_vT<<<tg, dim3(32, 8), 0, stream>>>(vals, vT, N, D);

  for (int row0 = 0; row0 < M; row0 += Mc) {
    const int mc = (M - row0) < Mc ? (M - row0) : Mc;
    // pass A: 128x256, BK=32, 2 blk/CU (2x work/block vs 128x128)
    const int g1 = (mc / 128) * (N / 256);
    rbf_gemm<0, 2, 4, 4, 32, 2><<<g1, 512, 0, stream>>>(
        xb + (size_t)row0 * D, pb, N, D, xsq, psq, rtemp, W, part, M,
        nullptr, nullptr, row0, N);
    reduce_denom<<<mc / 128, 128, 0, stream>>>(part, denom, M, row0, S);
    // pass B: 128x256, BK=64 (round-12 proven config)
    const int g2 = (mc / 128) * (D / 256);
    rbf_gemm<1, 2, 4, 4, 64, 2><<<g2, 512, 0, stream>>>(
        W, vT, D, N, nullptr, nullptr, nullptr, nullptr,
        part, M, denom, out, row0, D);
  }
}

// Round 16
// 205.983 us; speedup vs baseline: 1.0869x; 1.0018x over previous
//
#include <hip/hip_runtime.h>
#include <hip/hip_bf16.h>

typedef __attribute__((ext_vector_type(8))) short short8;
typedef __attribute__((ext_vector_type(4))) float f32x4;
typedef __attribute__((ext_vector_type(4))) unsigned short u16x4;

__device__ __forceinline__ unsigned short f2bf(float f) {
  union { float f; unsigned u; } v; v.f = f;
  unsigned r = v.u + 0x7fffu + ((v.u >> 16) & 1u);
  return (unsigned short)(r >> 16);
}

// C = A * Bt^T. WM*WN waves, wave-tile (MI*16) x 64, NBUF-deep circular LDS
// staging with counted vmcnt (prefetch stays in flight over MFMA), setprio.
// bn-MAJOR linear block mapping: XCD round-robin gives each XCD a recurring
// set of A-panels (L2-resident) and concurrent blocks share the B-panel.
// Pass A: EPI=0, WM=2,WN=4,MI=4,BK=32,NBUF=3 -> 128x256, 72 KB LDS,
//   2 blk/CU, 2-deep prefetch (covers the L2 round-trip per K-step).
//   Epilogue: w = exp2(-dist*rt2), W bf16 via swizzled LDS bounce -> cached
//   stores (pass B re-reads W); row-sum partials (unique writer).
// Pass B: EPI=1, WM=2,WN=4,MI=4,BK=64,NBUF=2 -> 128x256 (proven config).
//   Epilogue: out fp32 * 1/(denin+1e-8) via LDS bounce -> NT stores.
// LDS staging swizzle: row r (CH x 16B chunks) holds global chunk c^(r&CMASK)
// at slot c; applied global-side (linear gload_lds dest) + reader-side.
template <int EPI, int WM, int WN, int MI, int BK, int NBUF>
__global__ __launch_bounds__(WM * WN * 64, 4) void rbf_gemm(
    const unsigned short* __restrict__ A, const unsigned short* __restrict__ Bt,
    int Ncols, int K,
    const float* __restrict__ xsq, const float* __restrict__ psq,
    const float* __restrict__ rtemp, unsigned short* __restrict__ Wout,
    float* __restrict__ part, int Mtot, const float* __restrict__ denin,
    float* __restrict__ outp, int row0, int ldOut) {
  constexpr int NT = WM * WN * 64;       // threads per block
  constexpr int BM = WM * MI * 16;
  constexpr int BN = WN * 64;
  constexpr int CH = BK / 8;             // 16B chunks per row
  constexpr int CMASK = CH - 1;
  constexpr int AIT = BM * CH / NT;      // A staging iters
  constexpr int BIT = BN * CH / NT;      // B staging iters
  constexpr int LOADS = AIT + BIT;
  constexpr int KS = BK / 32;            // k-frags per step
  constexpr int ASZ = BM * BK;
  constexpr int TSZ = (BM + BN) * BK;    // elems per buffer
  constexpr int BOUNCE = EPI == 1 ? BM * BN * 2 : BM * BN;  // shorts
  constexpr int SELEMS = NBUF * TSZ > BOUNCE ? NBUF * TSZ : BOUNCE;
  __shared__ __align__(16) unsigned short smem[SELEMS];

  const int t = threadIdx.x;
  const int lane = t & 63, wid = t >> 6;
  const int wm = wid / WN, wn = wid % WN;
  const int lr = lane & 15, lg = lane >> 4;

  // bn-major mapping: consecutive blocks share bn and walk bm.
  const int nbm = gridDim.x / (Ncols / BN);
  const int bm = blockIdx.x % nbm;
  const int bn = blockIdx.x / nbm;

  const unsigned short* Ab = A + (size_t)bm * BM * K;
  const unsigned short* Bb = Bt + (size_t)bn * BN * K;

  // staging source pointers (swizzled chunk); bumped by +BK per stage
  const unsigned short* gA[AIT];
  const unsigned short* gB[BIT];
#pragma unroll
  for (int i = 0; i < AIT; ++i) {
    const int idx = i * NT + t;
    const int r = idx / CH, c = idx & CMASK;
    gA[i] = Ab + (size_t)r * K + ((c ^ (r & CMASK)) << 3);
  }
#pragma unroll
  for (int i = 0; i < BIT; ++i) {
    const int idx = i * NT + t;
    const int r = idx / CH, c = idx & CMASK;
    gB[i] = Bb + (size_t)r * K + ((c ^ (r & CMASK)) << 3);
  }
  const int dwave = wid << 9;  // wave-uniform LDS elem base (64 lanes * 16B)

  // fragment LDS element offsets (reader applies same swizzle)
  int offA[MI][KS], offB[4][KS];
#pragma unroll
  for (int mi = 0; mi < MI; ++mi) {
    const int ar = wm * (MI * 16) + mi * 16 + lr;
#pragma unroll
    for (int ks = 0; ks < KS; ++ks)
      offA[mi][ks] = ar * BK + ((((ks << 2) | lg) ^ (ar & CMASK)) << 3);
  }
#pragma unroll
  for (int ni = 0; ni < 4; ++ni) {
    const int br = wn * 64 + ni * 16 + lr;
#pragma unroll
    for (int ks = 0; ks < KS; ++ks)
      offB[ni][ks] = ASZ + br * BK + ((((ks << 2) | lg) ^ (br & CMASK)) << 3);
  }

  f32x4 acc[MI][4];
#pragma unroll
  for (int i = 0; i < MI; ++i)
#pragma unroll
    for (int j = 0; j < 4; ++j) acc[i][j] = (f32x4){0.f, 0.f, 0.f, 0.f};

  // STAGE issues from current gA/gB then bumps them by BK.
#define STAGE(bo)                                                                      \
  do {                                                                                 \
    _Pragma("unroll")                                                                  \
    for (int i = 0; i < AIT; ++i) {                                                    \
      __builtin_amdgcn_global_load_lds(                                                \
          (const __attribute__((address_space(1))) void*)gA[i],                        \
          (__attribute__((address_space(3))) void*)(smem + (bo) + i * (NT * 8) + dwave), \
          16, 0, 0);                                                                   \
      gA[i] += BK;                                                                     \
    }                                                                                  \
    _Pragma("unroll")                                                                  \
    for (int i = 0; i < BIT; ++i) {                                                    \
      __builtin_amdgcn_global_load_lds(                                                \
          (const __attribute__((address_space(1))) void*)gB[i],                        \
          (__attribute__((address_space(3))) void*)(smem + (bo) + ASZ + i * (NT * 8) + dwave), \
          16, 0, 0);                                                                   \
      gB[i] += BK;                                                                     \
    }                                                                                  \
  } while (0)

  const int nsteps = K / BK;
  // prologue: issue NBUF-1 stages
#pragma unroll
  for (int p = 0; p < NBUF - 1; ++p)
    if (p < nsteps) STAGE(p * TSZ);

  int bc = 0, bp = (NBUF - 1) % NBUF;  // current / prefetch-dest buffers
  for (int s = 0; s < nsteps; ++s) {
    if (s + NBUF - 1 < nsteps) {
      STAGE(bp * TSZ);  // prefetch; stays in flight over MFMA
      asm volatile("s_waitcnt vmcnt(%0)" :: "i"((NBUF - 1) * LOADS) : "memory");
    } else if (NBUF >= 3 && s + 1 < nsteps) {
      asm volatile("s_waitcnt vmcnt(%0)" :: "i"(LOADS) : "memory");
    } else {
      asm volatile("s_waitcnt vmcnt(0)" ::: "memory");
    }
    __builtin_amdgcn_s_barrier();       // all waves' stage(s) landed
    const unsigned short* sb = smem + bc * TSZ;
    __builtin_amdgcn_s_setprio(1);
#pragma unroll
    for (int ks = 0; ks < KS; ++ks) {
      short8 af[MI], bf[4];
#pragma unroll
      for (int mi = 0; mi < MI; ++mi) af[mi] = *(const short8*)&sb[offA[mi][ks]];
#pragma unroll
      for (int ni = 0; ni < 4; ++ni) bf[ni] = *(const short8*)&sb[offB[ni][ks]];
#pragma unroll
      for (int mi = 0; mi < MI; ++mi)
#pragma unroll
        for (int ni = 0; ni < 4; ++ni)
          acc[mi][ni] = __builtin_amdgcn_mfma_f32_16x16x32_bf16(af[mi], bf[ni],
                                                                acc[mi][ni], 0, 0, 0);
    }
    __builtin_amdgcn_s_setprio(0);
    asm volatile("s_waitcnt lgkmcnt(0)" ::: "memory");  // ds_reads drained
    __builtin_amdgcn_s_barrier();       // safe to overwrite bc later
    bc = bc + 1 == NBUF ? 0 : bc + 1;
    bp = bp + 1 == NBUF ? 0 : bp + 1;
  }
#undef STAGE

  if (EPI == 0) {
    // cross -> dist -> weight -> swizzled LDS bounce; per-row partial sums.
    float ps[4], rt[4];
#pragma unroll
    for (int ni = 0; ni < 4; ++ni) {
      const int col = bn * BN + wn * 64 + ni * 16 + lr;
      ps[ni] = psq[col];
      rt[ni] = rtemp[col];  // log2e / effective_temp
    }
    float* slice = part + (size_t)(bn * WN + wn) * Mtot;
#pragma unroll
    for (int mi = 0; mi < MI; ++mi) {
#pragma unroll
      for (int j = 0; j < 4; ++j) {
        const int lrow = wm * (MI * 16) + mi * 16 + lg * 4 + j;
        const int grow = row0 + bm * BM + lrow;
        const float xq = xsq[grow];
        float rsv = 0.f;
#pragma unroll
        for (int ni = 0; ni < 4; ++ni) {
          const int lcol = wn * 64 + ni * 16 + lr;
          float d2 = xq + ps[ni] - 2.0f * acc[mi][ni][j];
          float dist = __builtin_amdgcn_sqrtf(fmaxf(d2, 0.0f));
          float w = __builtin_amdgcn_exp2f(-dist * rt[ni]);
          smem[lrow * BN + (((lcol >> 3) ^ (lrow & 7)) << 3) + (lcol & 7)] = f2bf(w);
          rsv += w;
        }
        rsv += __shfl_xor(rsv, 1);
        rsv += __shfl_xor(rsv, 2);
        rsv += __shfl_xor(rsv, 4);
        rsv += __shfl_xor(rsv, 8);
        if (lr == 0) slice[grow] = rsv;
      }
    }
    __syncthreads();
    // coalesced cached copy-out (W re-read by pass B)
    constexpr int HB = BN / 8;
#pragma unroll
    for (int i = 0; i < BM * BN / 8 / NT; ++i) {
      const int id = i * NT + t;
      const int r = id / HB, h = id % HB;
      short8 v = *(const short8*)&smem[r * BN + ((h ^ (r & 7)) << 3)];
      *(short8*)&Wout[(size_t)(bm * BM + r) * ldOut + bn * BN + h * 8] = v;
    }
  } else {
    // scale by 1/denom at copy-out; bounce fp32 tile for full-line NT stores
    float* smemf = (float*)smem;
#pragma unroll
    for (int mi = 0; mi < MI; ++mi)
#pragma unroll
      for (int j = 0; j < 4; ++j) {
        const int lrow = wm * (MI * 16) + mi * 16 + lg * 4 + j;
#pragma unroll
        for (int ni = 0; ni < 4; ++ni) {
          const int lcol = wn * 64 + ni * 16 + lr;
          smemf[lrow * BN + (((lcol >> 2) ^ (lrow & 7)) << 2) + (lcol & 3)] =
              acc[mi][ni][j];
        }
      }
    __syncthreads();
    constexpr int HB4 = BN / 4;
#pragma unroll
    for (int i = 0; i < BM * BN / 4 / NT; ++i) {
      const int id = i * NT + t;
      const int r = id / HB4, h = id % HB4;
      const int grow = row0 + bm * BM + r;
      const float rd = 1.0f / (denin[grow] + 1e-8f);
      f32x4 v = *(const f32x4*)&smemf[r * BN + ((h ^ (r & 7)) << 2)];
      v *= rd;
      __builtin_nontemporal_store(v,
          (f32x4*)&outp[(size_t)grow * ldOut + bn * BN + h * 4]);
    }
  }
}

// denom[m] = sum_s part[s][m]
__global__ void reduce_denom(const float* __restrict__ part, float* __restrict__ denom,
                             int Mtot, int row0, int S) {
  const int m = row0 + blockIdx.x * 128 + threadIdx.x;
  float s = 0.f;
  for (int i = 0; i < S; ++i) s += part[(size_t)i * Mtot + m];
  denom[m] = s;
}

// Merged prep: rows [0,M) from x, rows [M,M+N) from pos.
// One block per row: cast fp32 row -> bf16, compute sum of squares.
__global__ void prep_rows2(const float* __restrict__ x, const float* __restrict__ pos,
                           unsigned short* __restrict__ xb, unsigned short* __restrict__ pb,
                           float* __restrict__ xsq, float* __restrict__ psq,
                           int D, int M) {
  const int row = blockIdx.x;
  const float* in;
  unsigned short* outb;
  float* sq;
  int r;
  if (row < M) {
    in = x; outb = xb; sq = xsq; r = row;
  } else {
    in = pos; outb = pb; sq = psq; r = row - M;
  }
  const int t = threadIdx.x;
  const float4 v = ((const float4*)(in + (size_t)r * D))[t];
  u16x4 o = {f2bf(v.x), f2bf(v.y), f2bf(v.z), f2bf(v.w)};
  *(u16x4*)(outb + (size_t)r * D + t * 4) = o;
  float s = v.x * v.x + v.y * v.y + v.z * v.z + v.w * v.w;
  for (int off = 32; off; off >>= 1) s += __shfl_xor(s, off);
  __shared__ float ws[16];
  if ((t & 63) == 0) ws[t >> 6] = s;
  __syncthreads();
  if (t == 0) {
    float tot = 0.f;
    const int nw = blockDim.x >> 6;
    for (int i = 0; i < nw; ++i) tot += ws[i];
    sq[r] = tot;
  }
}

// rtemp = log2(e) / ((|T|+0.1)*scale): folds the exp->exp2 conversion.
__global__ void prep_scale(const float* __restrict__ tmp, const float* __restrict__ sc,
                           float* __restrict__ rtemp, int N) {
  const int i = blockIdx.x * blockDim.x + threadIdx.x;
  if (i < N) rtemp[i] = 1.4426950408889634f / ((fabsf(tmp[i]) + 0.1f) * sc[i]);
}

// Transpose values [N][D] fp32 -> vT [D][N] bf16
__global__ void prep_vT(const float* __restrict__ vals, unsigned short* __restrict__ vT,
                        int N, int D) {
  __shared__ float tile[32][33];
  const int nt = blockIdx.x, dt = blockIdx.y;
  const int tx = threadIdx.x, ty = threadIdx.y;  // (32, 8)
#pragma unroll
  for (int i = 0; i < 4; ++i) {
    int r = nt * 32 + ty + i * 8;
    tile[ty + i * 8][tx] = vals[(size_t)r * D + dt * 32 + tx];
  }
  __syncthreads();
#pragma unroll
  for (int i = 0; i < 4; ++i) {
    int d = dt * 32 + ty + i * 8;
    vT[(size_t)d * N + nt * 32 + tx] = f2bf(tile[tx][ty + i * 8]);
  }
}

extern "C" void kernel_launch(void* const* d_in, const int* in_sizes, int n_in,
                              void* d_out, int out_size, void* d_ws, size_t ws_size,
                              hipStream_t stream) {
  const float* x = (const float*)d_in[0];
  const float* pos = (const float*)d_in[1];
  const float* vals = (const float*)d_in[2];
  const float* temp = (const float*)d_in[3];
  const float* nsc = (const float*)d_in[4];
  float* out = (float*)d_out;

  const int N = in_sizes[3];          // 4096
  const int D = in_sizes[1] / N;      // 512
  const int M = in_sizes[0] / D;      // 16384
  const int S = 4 * (N / 256);        // partial slices (64): BN=256, WN=4

  char* ws = (char*)d_ws;
  size_t off = 0;
  auto alloc = [&](size_t bytes) {
    void* p = ws + off;
    off = (off + bytes + 255) & ~(size_t)255;
    return p;
  };
  unsigned short* xb = (unsigned short*)alloc((size_t)M * D * 2);
  unsigned short* pb = (unsigned short*)alloc((size_t)N * D * 2);
  unsigned short* vT = (unsigned short*)alloc((size_t)D * N * 2);
  float* xsq = (float*)alloc((size_t)M * 4);
  float* psq = (float*)alloc((size_t)N * 4);
  float* rtemp = (float*)alloc((size_t)N * 4);
  float* denom = (float*)alloc((size_t)M * 4);
  float* part = (float*)alloc((size_t)S * M * 4);

  size_t avail = ws_size > off ? ws_size - off : 0;
  long long mc_ll = (long long)(avail / ((size_t)N * 2));
  int Mc = (int)((mc_ll / 128) * 128);
  if (Mc > M) Mc = M;
  if (Mc < 128) Mc = 128;  // minimal fallback
  unsigned short* W = (unsigned short*)alloc((size_t)Mc * N * 2);

  prep_rows2<<<M + N, D / 4, 0, stream>>>(x, pos, xb, pb, xsq, psq, D, M);
  prep_scale<<<(N + 255) / 256, 256, 0, stream>>>(temp, nsc, rtemp, N);
  dim3 tg(N / 32, D / 32);
  prep_vT<<<tg, dim3(32, 8), 0, stream>>>(vals, vT, N, D);

  for (int row0 = 0; row0 < M; row0 += Mc) {
    const int mc = (M - row0) < Mc ? (M - row0) : Mc;
    // pass A: 128x256, BK=32, NBUF=3 (2-deep prefetch), 2 blk/CU
    const int g1 = (mc / 128) * (N / 256);
    rbf_gemm<0, 2, 4, 4, 32, 3><<<g1, 512, 0, stream>>>(
        xb + (size_t)row0 * D, pb, N, D, xsq, psq, rtemp, W, part, M,
        nullptr, nullptr, row0, N);
    reduce_denom<<<mc / 128, 128, 0, stream>>>(part, denom, M, row0, S);
    // pass B: 128x256, BK=64 (proven config)
    const int g2 = (mc / 128) * (D / 256);
    rbf_gemm<1, 2, 4, 4, 64, 2><<<g2, 512, 0, stream>>>(
        W, vT, D, N, nullptr, nullptr, nullptr, nullptr,
        part, M, denom, out, row0, D);
  }
}